// Round 1
// baseline (847.221 us; speedup 1.0000x reference)
//
#include <hip/hip_runtime.h>
#include <hip/hip_bf16.h>

#define NN 50000
#define NE 800000
#define FIN 128
#define HC 256
#define NEG_SLOPE 0.2f

// ---------------- GEMM: C[M,256] = A[M,K] @ B[K,256] (no bias) ----------------
#define BM 128
#define BN 128
#define BK 32

__global__ __launch_bounds__(256) void gemm_kernel(
    const float* __restrict__ A, const float* __restrict__ B,
    float* __restrict__ C, int M, int K) {
  __shared__ float sA[BK][BM + 4];      // [k][m], +4 pad keeps 16B align, reduces store conflicts
  __shared__ float4 sB[BK][2][16];      // [k][half][tx] : col = tx*8 + half*4 + i

  int t = threadIdx.x;
  int tx = t & 15, ty = t >> 4;
  int m0 = blockIdx.x * BM;
  int n0 = blockIdx.y * BN;

  float acc[8][8];
#pragma unroll
  for (int i = 0; i < 8; ++i)
#pragma unroll
    for (int j = 0; j < 8; ++j) acc[i][j] = 0.f;

  for (int k0 = 0; k0 < K; k0 += BK) {
    // stage A tile: 128 rows x 32 k
#pragma unroll
    for (int i = 0; i < 4; ++i) {
      int row = (t >> 3) + i * 32;
      int kk = (t & 7) * 4;
      int gr = m0 + row;
      float4 v = {0.f, 0.f, 0.f, 0.f};
      if (gr < M) v = *(const float4*)(A + (size_t)gr * K + k0 + kk);
      sA[kk + 0][row] = v.x;
      sA[kk + 1][row] = v.y;
      sA[kk + 2][row] = v.z;
      sA[kk + 3][row] = v.w;
    }
    // stage B tile: 32 k x 128 n
#pragma unroll
    for (int i = 0; i < 4; ++i) {
      int kr = (t >> 5) + i * 8;
      int col = (t & 31) * 4;
      float4 v = *(const float4*)(B + (size_t)(k0 + kr) * HC + n0 + col);
      sB[kr][(col >> 2) & 1][col >> 3] = v;
    }
    __syncthreads();
#pragma unroll
    for (int k = 0; k < BK; ++k) {
      float4 a0 = *(const float4*)&sA[k][ty * 8];
      float4 a1 = *(const float4*)&sA[k][ty * 8 + 4];
      float4 b0 = sB[k][0][tx];
      float4 b1 = sB[k][1][tx];
      float a[8] = {a0.x, a0.y, a0.z, a0.w, a1.x, a1.y, a1.z, a1.w};
      float b[8] = {b0.x, b0.y, b0.z, b0.w, b1.x, b1.y, b1.z, b1.w};
#pragma unroll
      for (int i = 0; i < 8; ++i)
#pragma unroll
        for (int j = 0; j < 8; ++j) acc[i][j] = fmaf(a[i], b[j], acc[i][j]);
    }
    __syncthreads();
  }
#pragma unroll
  for (int i = 0; i < 8; ++i) {
    int gr = m0 + ty * 8 + i;
    if (gr < M) {
      float4 o0 = {acc[i][0], acc[i][1], acc[i][2], acc[i][3]};
      float4 o1 = {acc[i][4], acc[i][5], acc[i][6], acc[i][7]};
      *(float4*)(C + (size_t)gr * HC + n0 + tx * 8) = o0;
      *(float4*)(C + (size_t)gr * HC + n0 + tx * 8 + 4) = o1;
    }
  }
}

// ------------- attention coefficients: a_s[n,h] = <h[n,h,:], att_src[h,:]> -------------
__global__ __launch_bounds__(256) void coef_kernel(
    const float* __restrict__ h, const float* __restrict__ att_s,
    const float* __restrict__ att_d, float* __restrict__ a_s,
    float* __restrict__ a_d) {
  int n = blockIdx.x * 4 + (threadIdx.x >> 6);
  if (n >= NN) return;
  int lane = threadIdx.x & 63;
  float4 hv = *(const float4*)(h + (size_t)n * HC + lane * 4);
  float4 s4 = *(const float4*)(att_s + lane * 4);
  float4 d4 = *(const float4*)(att_d + lane * 4);
  float ps = hv.x * s4.x + hv.y * s4.y + hv.z * s4.z + hv.w * s4.w;
  float pd = hv.x * d4.x + hv.y * d4.y + hv.z * d4.z + hv.w * d4.w;
#pragma unroll
  for (int off = 1; off <= 4; off <<= 1) {
    ps += __shfl_xor(ps, off);
    pd += __shfl_xor(pd, off);
  }
  if ((lane & 7) == 0) {
    a_s[n * 8 + (lane >> 3)] = ps;
    a_d[n * 8 + (lane >> 3)] = pd;
  }
}

// ---------------- CSR build (dst-major), self-loops via counts init = 1 ----------------
__global__ void init_counts(int* counts, int* tmp) {
  int i = blockIdx.x * 256 + threadIdx.x;
  if (i < NN) { counts[i] = 1; tmp[i] = 0; }
}

__global__ void hist_kernel(const int* __restrict__ ei, int* __restrict__ counts) {
  int e = blockIdx.x * 256 + threadIdx.x;
  if (e < NE) atomicAdd(&counts[ei[NE + e]], 1);
}

__global__ void scan1(const int* __restrict__ counts, int* __restrict__ scanbuf,
                      int* __restrict__ bsum) {
  __shared__ int sd[256];
  int t = threadIdx.x;
  int i = blockIdx.x * 256 + t;
  int v = (i < NN) ? counts[i] : 0;
  sd[t] = v;
  __syncthreads();
#pragma unroll
  for (int off = 1; off < 256; off <<= 1) {
    int x = (t >= off) ? sd[t - off] : 0;
    __syncthreads();
    sd[t] += x;
    __syncthreads();
  }
  if (i < NN) scanbuf[i] = sd[t];
  if (t == 255) bsum[blockIdx.x] = sd[255];
}

__global__ void scan2(const int* __restrict__ bsum, int* __restrict__ boff, int nb) {
  __shared__ int sd[256];
  int t = threadIdx.x;
  int v = (t < nb) ? bsum[t] : 0;
  sd[t] = v;
  __syncthreads();
#pragma unroll
  for (int off = 1; off < 256; off <<= 1) {
    int x = (t >= off) ? sd[t - off] : 0;
    __syncthreads();
    sd[t] += x;
    __syncthreads();
  }
  if (t < nb) boff[t] = sd[t] - v;  // exclusive
}

__global__ void scan3(const int* __restrict__ scanbuf, const int* __restrict__ boff,
                      int* __restrict__ rowptr) {
  int i = blockIdx.x * 256 + threadIdx.x;
  if (i < NN) rowptr[i + 1] = scanbuf[i] + boff[blockIdx.x];
  if (i == 0) rowptr[0] = 0;
}

__global__ void scatter_kernel(const int* __restrict__ ei, const int* __restrict__ rowptr,
                               int* __restrict__ tmp, int* __restrict__ col) {
  int e = blockIdx.x * 256 + threadIdx.x;
  if (e >= NE + NN) return;
  int s, d;
  if (e < NE) { s = ei[e]; d = ei[NE + e]; }
  else { s = d = e - NE; }
  int pos = rowptr[d] + atomicAdd(&tmp[d], 1);
  col[pos] = s;
}

// ---------------- aggregation: wave per dst node, online softmax ----------------
__global__ __launch_bounds__(256) void agg_kernel(
    const float* __restrict__ ht, const float* __restrict__ a_s,
    const float* __restrict__ a_d, const int* __restrict__ rowptr,
    const int* __restrict__ col, const float* __restrict__ bias,
    float* __restrict__ out) {
  int d = blockIdx.x * 4 + (threadIdx.x >> 6);
  if (d >= NN) return;
  int lane = threadIdx.x & 63;
  int hh = lane >> 3;  // head; lane covers global channels [lane*4, lane*4+3]
  float adh = a_d[d * 8 + hh];
  int r0 = rowptr[d], r1 = rowptr[d + 1];
  float m = -1e30f, denom = 0.f;
  float4 acc = {0.f, 0.f, 0.f, 0.f};
  for (int r = r0; r < r1; ++r) {
    int s = col[r];
    float e = a_s[s * 8 + hh] + adh;
    e = e > 0.f ? e : NEG_SLOPE * e;
    float mn = fmaxf(m, e);
    float corr = __expf(m - mn);  // first iter: exp(-huge) = 0
    float w = __expf(e - mn);
    denom = denom * corr + w;
    float4 hv = *(const float4*)(ht + (size_t)s * HC + lane * 4);
    acc.x = acc.x * corr + w * hv.x;
    acc.y = acc.y * corr + w * hv.y;
    acc.z = acc.z * corr + w * hv.z;
    acc.w = acc.w * corr + w * hv.w;
    m = mn;
  }
  float inv = 1.f / denom;  // denom >= 1 (self-loop)
  float4 b4 = *(const float4*)(bias + lane * 4);
  float4 o;
  o.x = fmaxf(fmaf(acc.x, inv, b4.x), 0.f);
  o.y = fmaxf(fmaf(acc.y, inv, b4.y), 0.f);
  o.z = fmaxf(fmaf(acc.z, inv, b4.z), 0.f);
  o.w = fmaxf(fmaf(acc.w, inv, b4.w), 0.f);
  *(float4*)(out + (size_t)d * HC + lane * 4) = o;
}

// ---------------- predictions ----------------
__global__ __launch_bounds__(256) void edge_pred_kernel(
    const float* __restrict__ h2, const int* __restrict__ ei,
    const float* __restrict__ We, const float* __restrict__ be,
    float* __restrict__ out) {
  int e = blockIdx.x * 4 + (threadIdx.x >> 6);
  if (e >= NE) return;
  int lane = threadIdx.x & 63;
  int s = ei[e], d = ei[NE + e];
  float4 hs = *(const float4*)(h2 + (size_t)s * HC + lane * 4);
  float4 hd = *(const float4*)(h2 + (size_t)d * HC + lane * 4);
  float4 we = *(const float4*)(We + lane * 4);
  float p = hs.x * hd.x * we.x + hs.y * hd.y * we.y + hs.z * hd.z * we.z +
            hs.w * hd.w * we.w;
#pragma unroll
  for (int off = 1; off <= 32; off <<= 1) p += __shfl_xor(p, off);
  if (lane == 0) out[e] = p + be[0];
}

__global__ __launch_bounds__(256) void node_pred_kernel(
    const float* __restrict__ h2, const float* __restrict__ Wn,
    const float* __restrict__ bn, float* __restrict__ out) {
  int n = blockIdx.x * 4 + (threadIdx.x >> 6);
  if (n >= NN) return;
  int lane = threadIdx.x & 63;
  float4 hv = *(const float4*)(h2 + (size_t)n * HC + lane * 4);
  float4 wn = *(const float4*)(Wn + lane * 4);
  float p = hv.x * wn.x + hv.y * wn.y + hv.z * wn.z + hv.w * wn.w;
#pragma unroll
  for (int off = 1; off <= 32; off <<= 1) p += __shfl_xor(p, off);
  if (lane == 0) out[n] = p;
}

extern "C" void kernel_launch(void* const* d_in, const int* in_sizes, int n_in,
                              void* d_out, int out_size, void* d_ws, size_t ws_size,
                              hipStream_t stream) {
  const float* x  = (const float*)d_in[0];
  const int* ei   = (const int*)d_in[1];   // [2,E]: first E = src, next E = dst
  const float* W1 = (const float*)d_in[3];
  const float* as1 = (const float*)d_in[4];
  const float* ad1 = (const float*)d_in[5];
  const float* b1 = (const float*)d_in[6];
  const float* W2 = (const float*)d_in[7];
  const float* as2 = (const float*)d_in[8];
  const float* ad2 = (const float*)d_in[9];
  const float* b2 = (const float*)d_in[10];
  const float* We = (const float*)d_in[11];
  const float* be = (const float*)d_in[12];
  const float* Wn = (const float*)d_in[13];
  const float* bn = (const float*)d_in[14];
  float* out = (float*)d_out;

  char* wsp = (char*)d_ws;
  auto alloc = [&](size_t bytes) {
    char* p = wsp;
    wsp += (bytes + 255) & ~(size_t)255;
    return p;
  };
  float* bufA = (float*)alloc((size_t)NN * HC * 4);  // transformed features
  float* bufB = (float*)alloc((size_t)NN * HC * 4);  // aggregated/activated
  float* a_s = (float*)alloc((size_t)NN * 8 * 4);
  float* a_d = (float*)alloc((size_t)NN * 8 * 4);
  int* rowptr = (int*)alloc((size_t)(NN + 1) * 4);
  int* colv = (int*)alloc((size_t)(NE + NN) * 4);
  int* counts = (int*)alloc((size_t)NN * 4);
  int* tmp = (int*)alloc((size_t)NN * 4);
  int* scanbuf = (int*)alloc((size_t)NN * 4);
  int* bsum = (int*)alloc(256 * 4);
  int* boff = (int*)alloc(256 * 4);

  const int NB = (NN + 255) / 256;  // 196

  // CSR build (dst-major, with self-loops)
  init_counts<<<NB, 256, 0, stream>>>(counts, tmp);
  hist_kernel<<<(NE + 255) / 256, 256, 0, stream>>>(ei, counts);
  scan1<<<NB, 256, 0, stream>>>(counts, scanbuf, bsum);
  scan2<<<1, 256, 0, stream>>>(bsum, boff, NB);
  scan3<<<NB, 256, 0, stream>>>(scanbuf, boff, rowptr);
  scatter_kernel<<<(NE + NN + 255) / 256, 256, 0, stream>>>(ei, rowptr, tmp, colv);

  dim3 ggrid((NN + BM - 1) / BM, HC / BN);  // 391 x 2

  // layer 1
  gemm_kernel<<<ggrid, 256, 0, stream>>>(x, W1, bufA, NN, FIN);
  coef_kernel<<<NN / 4, 256, 0, stream>>>(bufA, as1, ad1, a_s, a_d);
  agg_kernel<<<NN / 4, 256, 0, stream>>>(bufA, a_s, a_d, rowptr, colv, b1, bufB);

  // layer 2
  gemm_kernel<<<ggrid, 256, 0, stream>>>(bufB, W2, bufA, NN, HC);
  coef_kernel<<<NN / 4, 256, 0, stream>>>(bufA, as2, ad2, a_s, a_d);
  agg_kernel<<<NN / 4, 256, 0, stream>>>(bufA, a_s, a_d, rowptr, colv, b2, bufB);

  // predictions
  edge_pred_kernel<<<NE / 4, 256, 0, stream>>>(bufB, ei, We, be, out);
  node_pred_kernel<<<NN / 4, 256, 0, stream>>>(bufB, Wn, bn, out + NE);
}

// Round 2
// 763.319 us; speedup vs baseline: 1.1099x; 1.1099x over previous
//
#include <hip/hip_runtime.h>
#include <hip/hip_bf16.h>

#define NN 50000
#define NE 800000
#define FIN 128
#define HC 256
#define NEG_SLOPE 0.2f

// ---------------- GEMM: C[M,256] = A[M,K] @ B[K,256] (no bias) ----------------
#define BM 128
#define BN 128
#define BK 32

__global__ __launch_bounds__(256) void gemm_kernel(
    const float* __restrict__ A, const float* __restrict__ B,
    float* __restrict__ C, int M, int K) {
  __shared__ float sA[BK][BM + 4];
  __shared__ float4 sB[BK][2][16];

  int t = threadIdx.x;
  int tx = t & 15, ty = t >> 4;
  int m0 = blockIdx.x * BM;
  int n0 = blockIdx.y * BN;

  float acc[8][8];
#pragma unroll
  for (int i = 0; i < 8; ++i)
#pragma unroll
    for (int j = 0; j < 8; ++j) acc[i][j] = 0.f;

  for (int k0 = 0; k0 < K; k0 += BK) {
#pragma unroll
    for (int i = 0; i < 4; ++i) {
      int row = (t >> 3) + i * 32;
      int kk = (t & 7) * 4;
      int gr = m0 + row;
      float4 v = {0.f, 0.f, 0.f, 0.f};
      if (gr < M) v = *(const float4*)(A + (size_t)gr * K + k0 + kk);
      sA[kk + 0][row] = v.x;
      sA[kk + 1][row] = v.y;
      sA[kk + 2][row] = v.z;
      sA[kk + 3][row] = v.w;
    }
#pragma unroll
    for (int i = 0; i < 4; ++i) {
      int kr = (t >> 5) + i * 8;
      int col = (t & 31) * 4;
      float4 v = *(const float4*)(B + (size_t)(k0 + kr) * HC + n0 + col);
      sB[kr][(col >> 2) & 1][col >> 3] = v;
    }
    __syncthreads();
#pragma unroll
    for (int k = 0; k < BK; ++k) {
      float4 a0 = *(const float4*)&sA[k][ty * 8];
      float4 a1 = *(const float4*)&sA[k][ty * 8 + 4];
      float4 b0 = sB[k][0][tx];
      float4 b1 = sB[k][1][tx];
      float a[8] = {a0.x, a0.y, a0.z, a0.w, a1.x, a1.y, a1.z, a1.w};
      float b[8] = {b0.x, b0.y, b0.z, b0.w, b1.x, b1.y, b1.z, b1.w};
#pragma unroll
      for (int i = 0; i < 8; ++i)
#pragma unroll
        for (int j = 0; j < 8; ++j) acc[i][j] = fmaf(a[i], b[j], acc[i][j]);
    }
    __syncthreads();
  }
#pragma unroll
  for (int i = 0; i < 8; ++i) {
    int gr = m0 + ty * 8 + i;
    if (gr < M) {
      float4 o0 = {acc[i][0], acc[i][1], acc[i][2], acc[i][3]};
      float4 o1 = {acc[i][4], acc[i][5], acc[i][6], acc[i][7]};
      *(float4*)(C + (size_t)gr * HC + n0 + tx * 8) = o0;
      *(float4*)(C + (size_t)gr * HC + n0 + tx * 8 + 4) = o1;
    }
  }
}

// ------------- attention coefficients -------------
__global__ __launch_bounds__(256) void coef_kernel(
    const float* __restrict__ h, const float* __restrict__ att_s,
    const float* __restrict__ att_d, float* __restrict__ a_s,
    float* __restrict__ a_d) {
  int n = blockIdx.x * 4 + (threadIdx.x >> 6);
  if (n >= NN) return;
  int lane = threadIdx.x & 63;
  float4 hv = *(const float4*)(h + (size_t)n * HC + lane * 4);
  float4 s4 = *(const float4*)(att_s + lane * 4);
  float4 d4 = *(const float4*)(att_d + lane * 4);
  float ps = hv.x * s4.x + hv.y * s4.y + hv.z * s4.z + hv.w * s4.w;
  float pd = hv.x * d4.x + hv.y * d4.y + hv.z * d4.z + hv.w * d4.w;
#pragma unroll
  for (int off = 1; off <= 4; off <<= 1) {
    ps += __shfl_xor(ps, off);
    pd += __shfl_xor(pd, off);
  }
  if ((lane & 7) == 0) {
    a_s[n * 8 + (lane >> 3)] = ps;
    a_d[n * 8 + (lane >> 3)] = pd;
  }
}

// ---------------- CSR build (dst-major), self-loops via counts init = 1 ----------------
__global__ void init_counts(int* counts, int* tmp) {
  int i = blockIdx.x * 256 + threadIdx.x;
  if (i < NN) { counts[i] = 1; tmp[i] = 0; }
}

__global__ void hist_kernel(const int* __restrict__ ei, int* __restrict__ counts) {
  int e = blockIdx.x * 256 + threadIdx.x;
  if (e < NE) atomicAdd(&counts[ei[NE + e]], 1);
}

__global__ void scan1(const int* __restrict__ counts, int* __restrict__ scanbuf,
                      int* __restrict__ bsum) {
  __shared__ int sd[256];
  int t = threadIdx.x;
  int i = blockIdx.x * 256 + t;
  int v = (i < NN) ? counts[i] : 0;
  sd[t] = v;
  __syncthreads();
#pragma unroll
  for (int off = 1; off < 256; off <<= 1) {
    int x = (t >= off) ? sd[t - off] : 0;
    __syncthreads();
    sd[t] += x;
    __syncthreads();
  }
  if (i < NN) scanbuf[i] = sd[t];
  if (t == 255) bsum[blockIdx.x] = sd[255];
}

__global__ void scan2(const int* __restrict__ bsum, int* __restrict__ boff, int nb) {
  __shared__ int sd[256];
  int t = threadIdx.x;
  int v = (t < nb) ? bsum[t] : 0;
  sd[t] = v;
  __syncthreads();
#pragma unroll
  for (int off = 1; off < 256; off <<= 1) {
    int x = (t >= off) ? sd[t - off] : 0;
    __syncthreads();
    sd[t] += x;
    __syncthreads();
  }
  if (t < nb) boff[t] = sd[t] - v;  // exclusive
}

__global__ void scan3(const int* __restrict__ scanbuf, const int* __restrict__ boff,
                      int* __restrict__ rowptr) {
  int i = blockIdx.x * 256 + threadIdx.x;
  if (i < NN) rowptr[i + 1] = scanbuf[i] + boff[blockIdx.x];
  if (i == 0) rowptr[0] = 0;
}

// also records the original edge id (-1 for self-loops) for CSR-ordered edge_pred
__global__ void scatter_kernel(const int* __restrict__ ei, const int* __restrict__ rowptr,
                               int* __restrict__ tmp, int* __restrict__ col,
                               int* __restrict__ eidv) {
  int e = blockIdx.x * 256 + threadIdx.x;
  if (e >= NE + NN) return;
  int s, d, id;
  if (e < NE) { s = ei[e]; d = ei[NE + e]; id = e; }
  else { s = d = e - NE; id = -1; }
  int pos = rowptr[d] + atomicAdd(&tmp[d], 1);
  col[pos] = s;
  eidv[pos] = id;
}

// ---------------- aggregation: wave per dst node, online softmax, 2-edge unroll ----------------
__global__ __launch_bounds__(256) void agg_kernel(
    const float* __restrict__ ht, const float* __restrict__ a_s,
    const float* __restrict__ a_d, const int* __restrict__ rowptr,
    const int* __restrict__ col, const float* __restrict__ bias,
    float* __restrict__ out) {
  int d = blockIdx.x * 4 + (threadIdx.x >> 6);
  if (d >= NN) return;
  int lane = threadIdx.x & 63;
  int hh = lane >> 3;
  float adh = a_d[d * 8 + hh];
  int r0 = rowptr[d], r1 = rowptr[d + 1];
  float m = -1e30f, denom = 0.f;
  float4 acc = {0.f, 0.f, 0.f, 0.f};
  int r = r0;
  for (; r + 1 < r1; r += 2) {
    int s0 = col[r], s1 = col[r + 1];
    float as0 = a_s[s0 * 8 + hh], as1 = a_s[s1 * 8 + hh];
    float4 h0 = *(const float4*)(ht + (size_t)s0 * HC + lane * 4);
    float4 h1 = *(const float4*)(ht + (size_t)s1 * HC + lane * 4);
    float e0 = as0 + adh; e0 = e0 > 0.f ? e0 : NEG_SLOPE * e0;
    float e1 = as1 + adh; e1 = e1 > 0.f ? e1 : NEG_SLOPE * e1;
    float mn = fmaxf(m, e0);
    float corr = __expf(m - mn);
    float w = __expf(e0 - mn);
    denom = denom * corr + w;
    acc.x = acc.x * corr + w * h0.x;
    acc.y = acc.y * corr + w * h0.y;
    acc.z = acc.z * corr + w * h0.z;
    acc.w = acc.w * corr + w * h0.w;
    m = mn;
    mn = fmaxf(m, e1);
    corr = __expf(m - mn);
    w = __expf(e1 - mn);
    denom = denom * corr + w;
    acc.x = acc.x * corr + w * h1.x;
    acc.y = acc.y * corr + w * h1.y;
    acc.z = acc.z * corr + w * h1.z;
    acc.w = acc.w * corr + w * h1.w;
    m = mn;
  }
  if (r < r1) {
    int s0 = col[r];
    float e0 = a_s[s0 * 8 + hh] + adh;
    e0 = e0 > 0.f ? e0 : NEG_SLOPE * e0;
    float4 h0 = *(const float4*)(ht + (size_t)s0 * HC + lane * 4);
    float mn = fmaxf(m, e0);
    float corr = __expf(m - mn);
    float w = __expf(e0 - mn);
    denom = denom * corr + w;
    acc.x = acc.x * corr + w * h0.x;
    acc.y = acc.y * corr + w * h0.y;
    acc.z = acc.z * corr + w * h0.z;
    acc.w = acc.w * corr + w * h0.w;
    m = mn;
  }
  float inv = 1.f / denom;
  float4 b4 = *(const float4*)(bias + lane * 4);
  float4 o;
  o.x = fmaxf(fmaf(acc.x, inv, b4.x), 0.f);
  o.y = fmaxf(fmaf(acc.y, inv, b4.y), 0.f);
  o.z = fmaxf(fmaf(acc.z, inv, b4.z), 0.f);
  o.w = fmaxf(fmaf(acc.w, inv, b4.w), 0.f);
  *(float4*)(out + (size_t)d * HC + lane * 4) = o;
}

// ---------------- edge predictions, CSR (dst-major) order ----------------
// wave per dst node: h2[d]*We kept in registers; stream src rows; scatter out[eid].
__global__ __launch_bounds__(256) void edge_pred_kernel(
    const float* __restrict__ h2, const int* __restrict__ rowptr,
    const int* __restrict__ col, const int* __restrict__ eidv,
    const float* __restrict__ We, const float* __restrict__ be,
    float* __restrict__ out) {
  int d = blockIdx.x * 4 + (threadIdx.x >> 6);
  if (d >= NN) return;
  int lane = threadIdx.x & 63;
  float4 hd = *(const float4*)(h2 + (size_t)d * HC + lane * 4);
  float4 we = *(const float4*)(We + lane * 4);
  float b = be[0];
  // premultiply dst row by We
  float4 wd = {hd.x * we.x, hd.y * we.y, hd.z * we.z, hd.w * we.w};
  int r0 = rowptr[d], r1 = rowptr[d + 1];
  int r = r0;
  for (; r + 1 < r1; r += 2) {
    int s0 = col[r], s1 = col[r + 1];
    int id0 = eidv[r], id1 = eidv[r + 1];
    float4 a = *(const float4*)(h2 + (size_t)s0 * HC + lane * 4);
    float4 c = *(const float4*)(h2 + (size_t)s1 * HC + lane * 4);
    float p0 = a.x * wd.x + a.y * wd.y + a.z * wd.z + a.w * wd.w;
    float p1 = c.x * wd.x + c.y * wd.y + c.z * wd.z + c.w * wd.w;
#pragma unroll
    for (int off = 1; off <= 32; off <<= 1) {
      p0 += __shfl_xor(p0, off);
      p1 += __shfl_xor(p1, off);
    }
    if (lane == 0 && id0 >= 0) out[id0] = p0 + b;
    if (lane == 0 && id1 >= 0) out[id1] = p1 + b;
  }
  if (r < r1) {
    int s0 = col[r];
    int id0 = eidv[r];
    float4 a = *(const float4*)(h2 + (size_t)s0 * HC + lane * 4);
    float p0 = a.x * wd.x + a.y * wd.y + a.z * wd.z + a.w * wd.w;
#pragma unroll
    for (int off = 1; off <= 32; off <<= 1) p0 += __shfl_xor(p0, off);
    if (lane == 0 && id0 >= 0) out[id0] = p0 + b;
  }
}

__global__ __launch_bounds__(256) void node_pred_kernel(
    const float* __restrict__ h2, const float* __restrict__ Wn,
    const float* __restrict__ bn, float* __restrict__ out) {
  int n = blockIdx.x * 4 + (threadIdx.x >> 6);
  if (n >= NN) return;
  int lane = threadIdx.x & 63;
  float4 hv = *(const float4*)(h2 + (size_t)n * HC + lane * 4);
  float4 wn = *(const float4*)(Wn + lane * 4);
  float p = hv.x * wn.x + hv.y * wn.y + hv.z * wn.z + hv.w * wn.w;
#pragma unroll
  for (int off = 1; off <= 32; off <<= 1) p += __shfl_xor(p, off);
  if (lane == 0) out[n] = p;
}

extern "C" void kernel_launch(void* const* d_in, const int* in_sizes, int n_in,
                              void* d_out, int out_size, void* d_ws, size_t ws_size,
                              hipStream_t stream) {
  const float* x  = (const float*)d_in[0];
  const int* ei   = (const int*)d_in[1];
  const float* W1 = (const float*)d_in[3];
  const float* as1 = (const float*)d_in[4];
  const float* ad1 = (const float*)d_in[5];
  const float* b1 = (const float*)d_in[6];
  const float* W2 = (const float*)d_in[7];
  const float* as2 = (const float*)d_in[8];
  const float* ad2 = (const float*)d_in[9];
  const float* b2 = (const float*)d_in[10];
  const float* We = (const float*)d_in[11];
  const float* be = (const float*)d_in[12];
  const float* Wn = (const float*)d_in[13];
  const float* bn = (const float*)d_in[14];
  float* out = (float*)d_out;

  char* wsp = (char*)d_ws;
  auto alloc = [&](size_t bytes) {
    char* p = wsp;
    wsp += (bytes + 255) & ~(size_t)255;
    return p;
  };
  float* bufA = (float*)alloc((size_t)NN * HC * 4);
  float* bufB = (float*)alloc((size_t)NN * HC * 4);
  float* a_s = (float*)alloc((size_t)NN * 8 * 4);
  float* a_d = (float*)alloc((size_t)NN * 8 * 4);
  int* rowptr = (int*)alloc((size_t)(NN + 1) * 4);
  int* colv = (int*)alloc((size_t)(NE + NN) * 4);
  int* eidv = (int*)alloc((size_t)(NE + NN) * 4);
  int* counts = (int*)alloc((size_t)NN * 4);
  int* tmp = (int*)alloc((size_t)NN * 4);
  int* scanbuf = (int*)alloc((size_t)NN * 4);
  int* bsum = (int*)alloc(256 * 4);
  int* boff = (int*)alloc(256 * 4);

  const int NB = (NN + 255) / 256;

  init_counts<<<NB, 256, 0, stream>>>(counts, tmp);
  hist_kernel<<<(NE + 255) / 256, 256, 0, stream>>>(ei, counts);
  scan1<<<NB, 256, 0, stream>>>(counts, scanbuf, bsum);
  scan2<<<1, 256, 0, stream>>>(bsum, boff, NB);
  scan3<<<NB, 256, 0, stream>>>(scanbuf, boff, rowptr);
  scatter_kernel<<<(NE + NN + 255) / 256, 256, 0, stream>>>(ei, rowptr, tmp, colv, eidv);

  dim3 ggrid((NN + BM - 1) / BM, HC / BN);

  gemm_kernel<<<ggrid, 256, 0, stream>>>(x, W1, bufA, NN, FIN);
  coef_kernel<<<NN / 4, 256, 0, stream>>>(bufA, as1, ad1, a_s, a_d);
  agg_kernel<<<NN / 4, 256, 0, stream>>>(bufA, a_s, a_d, rowptr, colv, b1, bufB);

  gemm_kernel<<<ggrid, 256, 0, stream>>>(bufB, W2, bufA, NN, HC);
  coef_kernel<<<NN / 4, 256, 0, stream>>>(bufA, as2, ad2, a_s, a_d);
  agg_kernel<<<NN / 4, 256, 0, stream>>>(bufA, a_s, a_d, rowptr, colv, b2, bufB);

  edge_pred_kernel<<<NN / 4, 256, 0, stream>>>(bufB, rowptr, colv, eidv, We, be, out);
  node_pred_kernel<<<NN / 4, 256, 0, stream>>>(bufB, Wn, bn, out + NE);
}

// Round 3
// 604.251 us; speedup vs baseline: 1.4021x; 1.2632x over previous
//
#include <hip/hip_runtime.h>
#include <hip/hip_bf16.h>

#define NN 50000
#define NE 800000
#define FIN 128
#define HC 256
#define NEG_SLOPE 0.2f

__device__ __forceinline__ unsigned short f2bf(float f) {
  unsigned u = __float_as_uint(f);
  u += 0x7fff + ((u >> 16) & 1);  // round-to-nearest-even
  return (unsigned short)(u >> 16);
}
__device__ __forceinline__ float bflo(unsigned u) {  // low 16 bits -> float
  return __uint_as_float(u << 16);
}
__device__ __forceinline__ float bfhi(unsigned u) {  // high 16 bits -> float
  return __uint_as_float(u & 0xffff0000u);
}

// ---------------- GEMM: C[M,256] = A[M,K] @ B[K,256]; also writes bf16 shadow Cb ----
#define BM 128
#define BN 128
#define BK 32

__global__ __launch_bounds__(256) void gemm_kernel(
    const float* __restrict__ A, const float* __restrict__ B,
    float* __restrict__ C, unsigned short* __restrict__ Cb, int M, int K) {
  __shared__ float sA[BK][BM + 4];
  __shared__ float4 sB[BK][2][16];

  int t = threadIdx.x;
  int tx = t & 15, ty = t >> 4;
  int m0 = blockIdx.x * BM;
  int n0 = blockIdx.y * BN;

  float acc[8][8];
#pragma unroll
  for (int i = 0; i < 8; ++i)
#pragma unroll
    for (int j = 0; j < 8; ++j) acc[i][j] = 0.f;

  for (int k0 = 0; k0 < K; k0 += BK) {
#pragma unroll
    for (int i = 0; i < 4; ++i) {
      int row = (t >> 3) + i * 32;
      int kk = (t & 7) * 4;
      int gr = m0 + row;
      float4 v = {0.f, 0.f, 0.f, 0.f};
      if (gr < M) v = *(const float4*)(A + (size_t)gr * K + k0 + kk);
      sA[kk + 0][row] = v.x;
      sA[kk + 1][row] = v.y;
      sA[kk + 2][row] = v.z;
      sA[kk + 3][row] = v.w;
    }
#pragma unroll
    for (int i = 0; i < 4; ++i) {
      int kr = (t >> 5) + i * 8;
      int col = (t & 31) * 4;
      float4 v = *(const float4*)(B + (size_t)(k0 + kr) * HC + n0 + col);
      sB[kr][(col >> 2) & 1][col >> 3] = v;
    }
    __syncthreads();
#pragma unroll
    for (int k = 0; k < BK; ++k) {
      float4 a0 = *(const float4*)&sA[k][ty * 8];
      float4 a1 = *(const float4*)&sA[k][ty * 8 + 4];
      float4 b0 = sB[k][0][tx];
      float4 b1 = sB[k][1][tx];
      float a[8] = {a0.x, a0.y, a0.z, a0.w, a1.x, a1.y, a1.z, a1.w};
      float b[8] = {b0.x, b0.y, b0.z, b0.w, b1.x, b1.y, b1.z, b1.w};
#pragma unroll
      for (int i = 0; i < 8; ++i)
#pragma unroll
        for (int j = 0; j < 8; ++j) acc[i][j] = fmaf(a[i], b[j], acc[i][j]);
    }
    __syncthreads();
  }
#pragma unroll
  for (int i = 0; i < 8; ++i) {
    int gr = m0 + ty * 8 + i;
    if (gr < M) {
      float4 o0 = {acc[i][0], acc[i][1], acc[i][2], acc[i][3]};
      float4 o1 = {acc[i][4], acc[i][5], acc[i][6], acc[i][7]};
      size_t off = (size_t)gr * HC + n0 + tx * 8;
      *(float4*)(C + off) = o0;
      *(float4*)(C + off + 4) = o1;
      uint4 pb;
      pb.x = (unsigned)f2bf(acc[i][0]) | ((unsigned)f2bf(acc[i][1]) << 16);
      pb.y = (unsigned)f2bf(acc[i][2]) | ((unsigned)f2bf(acc[i][3]) << 16);
      pb.z = (unsigned)f2bf(acc[i][4]) | ((unsigned)f2bf(acc[i][5]) << 16);
      pb.w = (unsigned)f2bf(acc[i][6]) | ((unsigned)f2bf(acc[i][7]) << 16);
      *(uint4*)(Cb + off) = pb;
    }
  }
}

// ------------- attention coefficients -------------
__global__ __launch_bounds__(256) void coef_kernel(
    const float* __restrict__ h, const float* __restrict__ att_s,
    const float* __restrict__ att_d, float* __restrict__ a_s,
    float* __restrict__ a_d) {
  int n = blockIdx.x * 4 + (threadIdx.x >> 6);
  if (n >= NN) return;
  int lane = threadIdx.x & 63;
  float4 hv = *(const float4*)(h + (size_t)n * HC + lane * 4);
  float4 s4 = *(const float4*)(att_s + lane * 4);
  float4 d4 = *(const float4*)(att_d + lane * 4);
  float ps = hv.x * s4.x + hv.y * s4.y + hv.z * s4.z + hv.w * s4.w;
  float pd = hv.x * d4.x + hv.y * d4.y + hv.z * d4.z + hv.w * d4.w;
#pragma unroll
  for (int off = 1; off <= 4; off <<= 1) {
    ps += __shfl_xor(ps, off);
    pd += __shfl_xor(pd, off);
  }
  if ((lane & 7) == 0) {
    a_s[n * 8 + (lane >> 3)] = ps;
    a_d[n * 8 + (lane >> 3)] = pd;
  }
}

// ---------------- CSR build (dst-major), self-loops via counts init = 1 ----------------
__global__ void init_counts(int* counts, int* tmp) {
  int i = blockIdx.x * 256 + threadIdx.x;
  if (i < NN) { counts[i] = 1; tmp[i] = 0; }
}

__global__ void hist_kernel(const int* __restrict__ ei, int* __restrict__ counts) {
  int e = blockIdx.x * 256 + threadIdx.x;
  if (e < NE) atomicAdd(&counts[ei[NE + e]], 1);
}

__global__ void scan1(const int* __restrict__ counts, int* __restrict__ scanbuf,
                      int* __restrict__ bsum) {
  __shared__ int sd[256];
  int t = threadIdx.x;
  int i = blockIdx.x * 256 + t;
  int v = (i < NN) ? counts[i] : 0;
  sd[t] = v;
  __syncthreads();
#pragma unroll
  for (int off = 1; off < 256; off <<= 1) {
    int x = (t >= off) ? sd[t - off] : 0;
    __syncthreads();
    sd[t] += x;
    __syncthreads();
  }
  if (i < NN) scanbuf[i] = sd[t];
  if (t == 255) bsum[blockIdx.x] = sd[255];
}

__global__ void scan2(const int* __restrict__ bsum, int* __restrict__ boff, int nb) {
  __shared__ int sd[256];
  int t = threadIdx.x;
  int v = (t < nb) ? bsum[t] : 0;
  sd[t] = v;
  __syncthreads();
#pragma unroll
  for (int off = 1; off < 256; off <<= 1) {
    int x = (t >= off) ? sd[t - off] : 0;
    __syncthreads();
    sd[t] += x;
    __syncthreads();
  }
  if (t < nb) boff[t] = sd[t] - v;  // exclusive
}

__global__ void scan3(const int* __restrict__ scanbuf, const int* __restrict__ boff,
                      int* __restrict__ rowptr) {
  int i = blockIdx.x * 256 + threadIdx.x;
  if (i < NN) rowptr[i + 1] = scanbuf[i] + boff[blockIdx.x];
  if (i == 0) rowptr[0] = 0;
}

__global__ void scatter_kernel(const int* __restrict__ ei, const int* __restrict__ rowptr,
                               int* __restrict__ tmp, int* __restrict__ col,
                               int* __restrict__ eidv) {
  int e = blockIdx.x * 256 + threadIdx.x;
  if (e >= NE + NN) return;
  int s, d, id;
  if (e < NE) { s = ei[e]; d = ei[NE + e]; id = e; }
  else { s = d = e - NE; id = -1; }
  int pos = rowptr[d] + atomicAdd(&tmp[d], 1);
  col[pos] = s;
  eidv[pos] = id;
}

// ---------------- aggregation: wave per dst node, online softmax, bf16 gathers ----------------
__global__ __launch_bounds__(256) void agg_kernel(
    const unsigned short* __restrict__ htb, const float* __restrict__ a_s,
    const float* __restrict__ a_d, const int* __restrict__ rowptr,
    const int* __restrict__ col, const float* __restrict__ bias,
    float* __restrict__ out, unsigned short* __restrict__ outb) {
  int d = blockIdx.x * 4 + (threadIdx.x >> 6);
  if (d >= NN) return;
  int lane = threadIdx.x & 63;
  int hh = lane >> 3;
  float adh = a_d[d * 8 + hh];
  int r0 = rowptr[d], r1 = rowptr[d + 1];
  float m = -1e30f, denom = 0.f;
  float4 acc = {0.f, 0.f, 0.f, 0.f};
  int r = r0;
  for (; r + 3 < r1; r += 4) {
    int s[4];
    float as_[4];
    uint2 q[4];
#pragma unroll
    for (int j = 0; j < 4; ++j) s[j] = col[r + j];
#pragma unroll
    for (int j = 0; j < 4; ++j) {
      as_[j] = a_s[s[j] * 8 + hh];
      q[j] = ((const uint2*)(htb + (size_t)s[j] * HC))[lane];
    }
#pragma unroll
    for (int j = 0; j < 4; ++j) {
      float e = as_[j] + adh;
      e = e > 0.f ? e : NEG_SLOPE * e;
      float mn = fmaxf(m, e);
      float corr = __expf(m - mn);
      float w = __expf(e - mn);
      denom = denom * corr + w;
      acc.x = acc.x * corr + w * bflo(q[j].x);
      acc.y = acc.y * corr + w * bfhi(q[j].x);
      acc.z = acc.z * corr + w * bflo(q[j].y);
      acc.w = acc.w * corr + w * bfhi(q[j].y);
      m = mn;
    }
  }
  for (; r < r1; ++r) {
    int s0 = col[r];
    float e = a_s[s0 * 8 + hh] + adh;
    e = e > 0.f ? e : NEG_SLOPE * e;
    uint2 q = ((const uint2*)(htb + (size_t)s0 * HC))[lane];
    float mn = fmaxf(m, e);
    float corr = __expf(m - mn);
    float w = __expf(e - mn);
    denom = denom * corr + w;
    acc.x = acc.x * corr + w * bflo(q.x);
    acc.y = acc.y * corr + w * bfhi(q.x);
    acc.z = acc.z * corr + w * bflo(q.y);
    acc.w = acc.w * corr + w * bfhi(q.y);
    m = mn;
  }
  float inv = 1.f / denom;
  float4 b4 = *(const float4*)(bias + lane * 4);
  float4 o;
  o.x = fmaxf(fmaf(acc.x, inv, b4.x), 0.f);
  o.y = fmaxf(fmaf(acc.y, inv, b4.y), 0.f);
  o.z = fmaxf(fmaf(acc.z, inv, b4.z), 0.f);
  o.w = fmaxf(fmaf(acc.w, inv, b4.w), 0.f);
  *(float4*)(out + (size_t)d * HC + lane * 4) = o;
  if (outb) {
    uint2 pb;
    pb.x = (unsigned)f2bf(o.x) | ((unsigned)f2bf(o.y) << 16);
    pb.y = (unsigned)f2bf(o.z) | ((unsigned)f2bf(o.w) << 16);
    ((uint2*)(outb + (size_t)d * HC))[lane] = pb;
  }
}

// ---------------- edge predictions, CSR order, bf16 src gathers ----------------
__global__ __launch_bounds__(256) void edge_pred_kernel(
    const float* __restrict__ h2, const unsigned short* __restrict__ h2b,
    const int* __restrict__ rowptr, const int* __restrict__ col,
    const int* __restrict__ eidv, const float* __restrict__ We,
    const float* __restrict__ be, float* __restrict__ out) {
  int d = blockIdx.x * 4 + (threadIdx.x >> 6);
  if (d >= NN) return;
  int lane = threadIdx.x & 63;
  float4 hd = *(const float4*)(h2 + (size_t)d * HC + lane * 4);
  float4 we = *(const float4*)(We + lane * 4);
  float b = be[0];
  float4 wd = {hd.x * we.x, hd.y * we.y, hd.z * we.z, hd.w * we.w};
  int r0 = rowptr[d], r1 = rowptr[d + 1];
  int r = r0;
  for (; r + 3 < r1; r += 4) {
    int s[4], id[4];
    uint2 q[4];
#pragma unroll
    for (int j = 0; j < 4; ++j) { s[j] = col[r + j]; id[j] = eidv[r + j]; }
#pragma unroll
    for (int j = 0; j < 4; ++j) q[j] = ((const uint2*)(h2b + (size_t)s[j] * HC))[lane];
    float p[4];
#pragma unroll
    for (int j = 0; j < 4; ++j) {
      p[j] = bflo(q[j].x) * wd.x + bfhi(q[j].x) * wd.y + bflo(q[j].y) * wd.z +
             bfhi(q[j].y) * wd.w;
    }
#pragma unroll
    for (int off = 1; off <= 32; off <<= 1) {
#pragma unroll
      for (int j = 0; j < 4; ++j) p[j] += __shfl_xor(p[j], off);
    }
    if (lane == 0) {
#pragma unroll
      for (int j = 0; j < 4; ++j)
        if (id[j] >= 0) out[id[j]] = p[j] + b;
    }
  }
  for (; r < r1; ++r) {
    int s0 = col[r];
    int id0 = eidv[r];
    uint2 q = ((const uint2*)(h2b + (size_t)s0 * HC))[lane];
    float p0 = bflo(q.x) * wd.x + bfhi(q.x) * wd.y + bflo(q.y) * wd.z +
               bfhi(q.y) * wd.w;
#pragma unroll
    for (int off = 1; off <= 32; off <<= 1) p0 += __shfl_xor(p0, off);
    if (lane == 0 && id0 >= 0) out[id0] = p0 + b;
  }
}

__global__ __launch_bounds__(256) void node_pred_kernel(
    const float* __restrict__ h2, const float* __restrict__ Wn,
    const float* __restrict__ bn, float* __restrict__ out) {
  int n = blockIdx.x * 4 + (threadIdx.x >> 6);
  if (n >= NN) return;
  int lane = threadIdx.x & 63;
  float4 hv = *(const float4*)(h2 + (size_t)n * HC + lane * 4);
  float4 wn = *(const float4*)(Wn + lane * 4);
  float p = hv.x * wn.x + hv.y * wn.y + hv.z * wn.z + hv.w * wn.w;
#pragma unroll
  for (int off = 1; off <= 32; off <<= 1) p += __shfl_xor(p, off);
  if (lane == 0) out[n] = p;
}

extern "C" void kernel_launch(void* const* d_in, const int* in_sizes, int n_in,
                              void* d_out, int out_size, void* d_ws, size_t ws_size,
                              hipStream_t stream) {
  const float* x  = (const float*)d_in[0];
  const int* ei   = (const int*)d_in[1];
  const float* W1 = (const float*)d_in[3];
  const float* as1 = (const float*)d_in[4];
  const float* ad1 = (const float*)d_in[5];
  const float* b1 = (const float*)d_in[6];
  const float* W2 = (const float*)d_in[7];
  const float* as2 = (const float*)d_in[8];
  const float* ad2 = (const float*)d_in[9];
  const float* b2 = (const float*)d_in[10];
  const float* We = (const float*)d_in[11];
  const float* be = (const float*)d_in[12];
  const float* Wn = (const float*)d_in[13];
  const float* bn = (const float*)d_in[14];
  float* out = (float*)d_out;

  char* wsp = (char*)d_ws;
  auto alloc = [&](size_t bytes) {
    char* p = wsp;
    wsp += (bytes + 255) & ~(size_t)255;
    return p;
  };
  float* bufA = (float*)alloc((size_t)NN * HC * 4);           // gemm output (fp32)
  float* bufB = (float*)alloc((size_t)NN * HC * 4);           // agg output (fp32)
  unsigned short* hbA = (unsigned short*)alloc((size_t)NN * HC * 2);  // bf16 shadow of bufA
  unsigned short* hbB = (unsigned short*)alloc((size_t)NN * HC * 2);  // bf16 shadow of h2
  float* a_s = (float*)alloc((size_t)NN * 8 * 4);
  float* a_d = (float*)alloc((size_t)NN * 8 * 4);
  int* rowptr = (int*)alloc((size_t)(NN + 1) * 4);
  int* colv = (int*)alloc((size_t)(NE + NN) * 4);
  int* eidv = (int*)alloc((size_t)(NE + NN) * 4);
  int* counts = (int*)alloc((size_t)NN * 4);
  int* tmp = (int*)alloc((size_t)NN * 4);
  int* scanbuf = (int*)alloc((size_t)NN * 4);
  int* bsum = (int*)alloc(256 * 4);
  int* boff = (int*)alloc(256 * 4);

  const int NB = (NN + 255) / 256;

  init_counts<<<NB, 256, 0, stream>>>(counts, tmp);
  hist_kernel<<<(NE + 255) / 256, 256, 0, stream>>>(ei, counts);
  scan1<<<NB, 256, 0, stream>>>(counts, scanbuf, bsum);
  scan2<<<1, 256, 0, stream>>>(bsum, boff, NB);
  scan3<<<NB, 256, 0, stream>>>(scanbuf, boff, rowptr);
  scatter_kernel<<<(NE + NN + 255) / 256, 256, 0, stream>>>(ei, rowptr, tmp, colv, eidv);

  dim3 ggrid((NN + BM - 1) / BM, HC / BN);

  // layer 1
  gemm_kernel<<<ggrid, 256, 0, stream>>>(x, W1, bufA, hbA, NN, FIN);
  coef_kernel<<<NN / 4, 256, 0, stream>>>(bufA, as1, ad1, a_s, a_d);
  agg_kernel<<<NN / 4, 256, 0, stream>>>(hbA, a_s, a_d, rowptr, colv, b1, bufB,
                                         (unsigned short*)nullptr);

  // layer 2
  gemm_kernel<<<ggrid, 256, 0, stream>>>(bufB, W2, bufA, hbA, NN, HC);
  coef_kernel<<<NN / 4, 256, 0, stream>>>(bufA, as2, ad2, a_s, a_d);
  agg_kernel<<<NN / 4, 256, 0, stream>>>(hbA, a_s, a_d, rowptr, colv, b2, bufB, hbB);

  // predictions
  edge_pred_kernel<<<NN / 4, 256, 0, stream>>>(bufB, hbB, rowptr, colv, eidv, We, be, out);
  node_pred_kernel<<<NN / 4, 256, 0, stream>>>(bufB, Wn, bn, out + NE);
}

// Round 4
// 515.073 us; speedup vs baseline: 1.6449x; 1.1731x over previous
//
#include <hip/hip_runtime.h>
#include <hip/hip_bf16.h>

#define NN 50000
#define NE 800000
#define FIN 128
#define HC 256
#define NEG_SLOPE 0.2f

typedef short bf16x8 __attribute__((ext_vector_type(8)));
typedef float f32x4 __attribute__((ext_vector_type(4)));

__device__ __forceinline__ unsigned short f2bf(float f) {
  unsigned u = __float_as_uint(f);
  u += 0x7fff + ((u >> 16) & 1);  // RTN-even
  return (unsigned short)(u >> 16);
}
__device__ __forceinline__ float bf2f(unsigned short s) {
  return __uint_as_float((unsigned)s << 16);
}
__device__ __forceinline__ float bflo(unsigned u) { return __uint_as_float(u << 16); }
__device__ __forceinline__ float bfhi(unsigned u) { return __uint_as_float(u & 0xffff0000u); }

// ---------------- input conversion: fp32 -> bf16 hi + bf16 residual ----------------
__global__ __launch_bounds__(256) void convert_x(const float* __restrict__ X,
                                                 unsigned short* __restrict__ Xh,
                                                 unsigned short* __restrict__ Xl,
                                                 int n4) {
  int i = blockIdx.x * 256 + threadIdx.x;
  if (i >= n4) return;
  float4 v = ((const float4*)X)[i];
  ushort4 h, l;
  h.x = f2bf(v.x); l.x = f2bf(v.x - bf2f(h.x));
  h.y = f2bf(v.y); l.y = f2bf(v.y - bf2f(h.y));
  h.z = f2bf(v.z); l.z = f2bf(v.z - bf2f(h.z));
  h.w = f2bf(v.w); l.w = f2bf(v.w - bf2f(h.w));
  ((ushort4*)Xh)[i] = h;
  ((ushort4*)Xl)[i] = l;
}

// W [K][HC] fp32 -> Wt hi/lo [HC][K] bf16 (transpose + split)
__global__ __launch_bounds__(256) void convert_w(const float* __restrict__ W,
                                                 unsigned short* __restrict__ Wth,
                                                 unsigned short* __restrict__ Wtl,
                                                 int K) {
  int i = blockIdx.x * 256 + threadIdx.x;
  if (i >= K * HC) return;
  int k = i / HC, n = i % HC;
  float v = W[i];
  unsigned short h = f2bf(v);
  Wth[n * K + k] = h;
  Wtl[n * K + k] = f2bf(v - bf2f(h));
}

// ---------------- MFMA GEMM: C[M,256] = (Ah+Al) @ (Bh+Bl)^T(stored [N][K]) ----------
// 128x128 block tile, 4 waves (each 64x64), 16x16x32 bf16 MFMA, 3-term split.
__global__ __launch_bounds__(256) void gemm_mfma(
    const unsigned short* __restrict__ Ah, const unsigned short* __restrict__ Al,
    const unsigned short* __restrict__ Bth, const unsigned short* __restrict__ Btl,
    float* __restrict__ C, unsigned short* __restrict__ Cb, int M, int K) {
  // LDS row stride 40 shorts (80 B): 16B-aligned, <=2-way bank alias (free)
  __shared__ unsigned short sAh[128 * 40];
  __shared__ unsigned short sAl[128 * 40];
  __shared__ unsigned short sBh[128 * 40];
  __shared__ unsigned short sBl[128 * 40];

  int t = threadIdx.x;
  int w = t >> 6, lane = t & 63;
  int quad = lane >> 4, lrow = lane & 15;
  int m0 = blockIdx.x * 128, n0 = blockIdx.y * 128;
  int wm = (w >> 1) * 64, wn = (w & 1) * 64;

  f32x4 acc[4][4] = {};

  for (int k0 = 0; k0 < K; k0 += 32) {
#pragma unroll
    for (int i = 0; i < 2; ++i) {
      int idx = t + i * 256;           // 0..511
      int row = idx >> 2, q = idx & 3; // row 0..127, q*8 shorts within 32-k tile
      int gm = m0 + row;
      if (gm >= M) gm = M - 1;
      size_t ga = (size_t)gm * K + k0 + q * 8;
      size_t gb = (size_t)(n0 + row) * K + k0 + q * 8;
      *(uint4*)(sAh + row * 40 + q * 8) = *(const uint4*)(Ah + ga);
      *(uint4*)(sAl + row * 40 + q * 8) = *(const uint4*)(Al + ga);
      *(uint4*)(sBh + row * 40 + q * 8) = *(const uint4*)(Bth + gb);
      *(uint4*)(sBl + row * 40 + q * 8) = *(const uint4*)(Btl + gb);
    }
    __syncthreads();

    bf16x8 fah[4], fal[4];
#pragma unroll
    for (int mi = 0; mi < 4; ++mi) {
      fah[mi] = *(const bf16x8*)(sAh + (wm + mi * 16 + lrow) * 40 + quad * 8);
      fal[mi] = *(const bf16x8*)(sAl + (wm + mi * 16 + lrow) * 40 + quad * 8);
    }
#pragma unroll
    for (int ni = 0; ni < 4; ++ni) {
      bf16x8 fbh = *(const bf16x8*)(sBh + (wn + ni * 16 + lrow) * 40 + quad * 8);
      bf16x8 fbl = *(const bf16x8*)(sBl + (wn + ni * 16 + lrow) * 40 + quad * 8);
#pragma unroll
      for (int mi = 0; mi < 4; ++mi) {
        acc[mi][ni] = __builtin_amdgcn_mfma_f32_16x16x32_bf16(fah[mi], fbh, acc[mi][ni], 0, 0, 0);
        acc[mi][ni] = __builtin_amdgcn_mfma_f32_16x16x32_bf16(fah[mi], fbl, acc[mi][ni], 0, 0, 0);
        acc[mi][ni] = __builtin_amdgcn_mfma_f32_16x16x32_bf16(fal[mi], fbh, acc[mi][ni], 0, 0, 0);
      }
    }
    __syncthreads();
  }

  // C/D layout: col = lane&15, row = quad*4 + reg  [m89-verified]
#pragma unroll
  for (int mi = 0; mi < 4; ++mi) {
#pragma unroll
    for (int r = 0; r < 4; ++r) {
      int gm = m0 + wm + mi * 16 + quad * 4 + r;
      if (gm < M) {
#pragma unroll
        for (int ni = 0; ni < 4; ++ni) {
          int gn = n0 + wn + ni * 16 + lrow;
          float v = acc[mi][ni][r];
          C[(size_t)gm * HC + gn] = v;
          Cb[(size_t)gm * HC + gn] = f2bf(v);
        }
      }
    }
  }
}

// ------------- attention coefficients -------------
__global__ __launch_bounds__(256) void coef_kernel(
    const float* __restrict__ h, const float* __restrict__ att_s,
    const float* __restrict__ att_d, float* __restrict__ a_s,
    float* __restrict__ a_d) {
  int n = blockIdx.x * 4 + (threadIdx.x >> 6);
  if (n >= NN) return;
  int lane = threadIdx.x & 63;
  float4 hv = *(const float4*)(h + (size_t)n * HC + lane * 4);
  float4 s4 = *(const float4*)(att_s + lane * 4);
  float4 d4 = *(const float4*)(att_d + lane * 4);
  float ps = hv.x * s4.x + hv.y * s4.y + hv.z * s4.z + hv.w * s4.w;
  float pd = hv.x * d4.x + hv.y * d4.y + hv.z * d4.z + hv.w * d4.w;
#pragma unroll
  for (int off = 1; off <= 4; off <<= 1) {
    ps += __shfl_xor(ps, off);
    pd += __shfl_xor(pd, off);
  }
  if ((lane & 7) == 0) {
    a_s[n * 8 + (lane >> 3)] = ps;
    a_d[n * 8 + (lane >> 3)] = pd;
  }
}

// ---------------- CSR build (dst-major), self-loops via counts init = 1 ----------------
__global__ void init_counts(int* counts, int* tmp) {
  int i = blockIdx.x * 256 + threadIdx.x;
  if (i < NN) { counts[i] = 1; tmp[i] = 0; }
}

__global__ void hist_kernel(const int* __restrict__ ei, int* __restrict__ counts) {
  int e = blockIdx.x * 256 + threadIdx.x;
  if (e < NE) atomicAdd(&counts[ei[NE + e]], 1);
}

__global__ void scan1(const int* __restrict__ counts, int* __restrict__ scanbuf,
                      int* __restrict__ bsum) {
  __shared__ int sd[256];
  int t = threadIdx.x;
  int i = blockIdx.x * 256 + t;
  int v = (i < NN) ? counts[i] : 0;
  sd[t] = v;
  __syncthreads();
#pragma unroll
  for (int off = 1; off < 256; off <<= 1) {
    int x = (t >= off) ? sd[t - off] : 0;
    __syncthreads();
    sd[t] += x;
    __syncthreads();
  }
  if (i < NN) scanbuf[i] = sd[t];
  if (t == 255) bsum[blockIdx.x] = sd[255];
}

__global__ void scan2(const int* __restrict__ bsum, int* __restrict__ boff, int nb) {
  __shared__ int sd[256];
  int t = threadIdx.x;
  int v = (t < nb) ? bsum[t] : 0;
  sd[t] = v;
  __syncthreads();
#pragma unroll
  for (int off = 1; off < 256; off <<= 1) {
    int x = (t >= off) ? sd[t - off] : 0;
    __syncthreads();
    sd[t] += x;
    __syncthreads();
  }
  if (t < nb) boff[t] = sd[t] - v;  // exclusive
}

__global__ void scan3(const int* __restrict__ scanbuf, const int* __restrict__ boff,
                      int* __restrict__ rowptr) {
  int i = blockIdx.x * 256 + threadIdx.x;
  if (i < NN) rowptr[i + 1] = scanbuf[i] + boff[blockIdx.x];
  if (i == 0) rowptr[0] = 0;
}

__global__ void scatter_kernel(const int* __restrict__ ei, const int* __restrict__ rowptr,
                               int* __restrict__ tmp, int* __restrict__ col,
                               int* __restrict__ eidv) {
  int e = blockIdx.x * 256 + threadIdx.x;
  if (e >= NE + NN) return;
  int s, d, id;
  if (e < NE) { s = ei[e]; d = ei[NE + e]; id = e; }
  else { s = d = e - NE; id = -1; }
  int pos = rowptr[d] + atomicAdd(&tmp[d], 1);
  col[pos] = s;
  eidv[pos] = id;
}

// ---------------- aggregation: wave per dst node, online softmax, bf16 gathers ----------------
// outputs (each may be null): outf fp32, outb bf16, outh/outl bf16 hi/lo split
__global__ __launch_bounds__(256) void agg_kernel(
    const unsigned short* __restrict__ htb, const float* __restrict__ a_s,
    const float* __restrict__ a_d, const int* __restrict__ rowptr,
    const int* __restrict__ col, const float* __restrict__ bias,
    float* __restrict__ outf, unsigned short* __restrict__ outb,
    unsigned short* __restrict__ outh, unsigned short* __restrict__ outl) {
  int d = blockIdx.x * 4 + (threadIdx.x >> 6);
  if (d >= NN) return;
  int lane = threadIdx.x & 63;
  int hh = lane >> 3;
  float adh = a_d[d * 8 + hh];
  int r0 = rowptr[d], r1 = rowptr[d + 1];
  float m = -1e30f, denom = 0.f;
  float4 acc = {0.f, 0.f, 0.f, 0.f};
  int r = r0;
  for (; r + 3 < r1; r += 4) {
    int s[4];
    float as_[4];
    uint2 q[4];
#pragma unroll
    for (int j = 0; j < 4; ++j) s[j] = col[r + j];
#pragma unroll
    for (int j = 0; j < 4; ++j) {
      as_[j] = a_s[s[j] * 8 + hh];
      q[j] = ((const uint2*)(htb + (size_t)s[j] * HC))[lane];
    }
#pragma unroll
    for (int j = 0; j < 4; ++j) {
      float e = as_[j] + adh;
      e = e > 0.f ? e : NEG_SLOPE * e;
      float mn = fmaxf(m, e);
      float corr = __expf(m - mn);
      float w = __expf(e - mn);
      denom = denom * corr + w;
      acc.x = acc.x * corr + w * bflo(q[j].x);
      acc.y = acc.y * corr + w * bfhi(q[j].x);
      acc.z = acc.z * corr + w * bflo(q[j].y);
      acc.w = acc.w * corr + w * bfhi(q[j].y);
      m = mn;
    }
  }
  for (; r < r1; ++r) {
    int s0 = col[r];
    float e = a_s[s0 * 8 + hh] + adh;
    e = e > 0.f ? e : NEG_SLOPE * e;
    uint2 q = ((const uint2*)(htb + (size_t)s0 * HC))[lane];
    float mn = fmaxf(m, e);
    float corr = __expf(m - mn);
    float w = __expf(e - mn);
    denom = denom * corr + w;
    acc.x = acc.x * corr + w * bflo(q.x);
    acc.y = acc.y * corr + w * bfhi(q.x);
    acc.z = acc.z * corr + w * bflo(q.y);
    acc.w = acc.w * corr + w * bfhi(q.y);
    m = mn;
  }
  float inv = 1.f / denom;
  float4 b4 = *(const float4*)(bias + lane * 4);
  float4 o;
  o.x = fmaxf(fmaf(acc.x, inv, b4.x), 0.f);
  o.y = fmaxf(fmaf(acc.y, inv, b4.y), 0.f);
  o.z = fmaxf(fmaf(acc.z, inv, b4.z), 0.f);
  o.w = fmaxf(fmaf(acc.w, inv, b4.w), 0.f);
  if (outf) *(float4*)(outf + (size_t)d * HC + lane * 4) = o;
  if (outb) {
    uint2 pb;
    pb.x = (unsigned)f2bf(o.x) | ((unsigned)f2bf(o.y) << 16);
    pb.y = (unsigned)f2bf(o.z) | ((unsigned)f2bf(o.w) << 16);
    ((uint2*)(outb + (size_t)d * HC))[lane] = pb;
  }
  if (outh) {
    unsigned short hx = f2bf(o.x), hy = f2bf(o.y), hz = f2bf(o.z), hw = f2bf(o.w);
    uint2 ph, pl;
    ph.x = (unsigned)hx | ((unsigned)hy << 16);
    ph.y = (unsigned)hz | ((unsigned)hw << 16);
    pl.x = (unsigned)f2bf(o.x - bf2f(hx)) | ((unsigned)f2bf(o.y - bf2f(hy)) << 16);
    pl.y = (unsigned)f2bf(o.z - bf2f(hz)) | ((unsigned)f2bf(o.w - bf2f(hw)) << 16);
    ((uint2*)(outh + (size_t)d * HC))[lane] = ph;
    ((uint2*)(outl + (size_t)d * HC))[lane] = pl;
  }
}

// ---------------- edge predictions, CSR order, bf16 gathers both sides ----------------
__global__ __launch_bounds__(256) void edge_pred_kernel(
    const unsigned short* __restrict__ h2b, const int* __restrict__ rowptr,
    const int* __restrict__ col, const int* __restrict__ eidv,
    const float* __restrict__ We, const float* __restrict__ be,
    float* __restrict__ out) {
  int d = blockIdx.x * 4 + (threadIdx.x >> 6);
  if (d >= NN) return;
  int lane = threadIdx.x & 63;
  uint2 qd = ((const uint2*)(h2b + (size_t)d * HC))[lane];
  float4 we = *(const float4*)(We + lane * 4);
  float b = be[0];
  float4 wd = {bflo(qd.x) * we.x, bfhi(qd.x) * we.y, bflo(qd.y) * we.z,
               bfhi(qd.y) * we.w};
  int r0 = rowptr[d], r1 = rowptr[d + 1];
  int r = r0;
  for (; r + 3 < r1; r += 4) {
    int s[4], id[4];
    uint2 q[4];
#pragma unroll
    for (int j = 0; j < 4; ++j) { s[j] = col[r + j]; id[j] = eidv[r + j]; }
#pragma unroll
    for (int j = 0; j < 4; ++j) q[j] = ((const uint2*)(h2b + (size_t)s[j] * HC))[lane];
    float p[4];
#pragma unroll
    for (int j = 0; j < 4; ++j) {
      p[j] = bflo(q[j].x) * wd.x + bfhi(q[j].x) * wd.y + bflo(q[j].y) * wd.z +
             bfhi(q[j].y) * wd.w;
    }
#pragma unroll
    for (int off = 1; off <= 32; off <<= 1) {
#pragma unroll
      for (int j = 0; j < 4; ++j) p[j] += __shfl_xor(p[j], off);
    }
    if (lane == 0) {
#pragma unroll
      for (int j = 0; j < 4; ++j)
        if (id[j] >= 0) out[id[j]] = p[j] + b;
    }
  }
  for (; r < r1; ++r) {
    int s0 = col[r];
    int id0 = eidv[r];
    uint2 q = ((const uint2*)(h2b + (size_t)s0 * HC))[lane];
    float p0 = bflo(q.x) * wd.x + bfhi(q.x) * wd.y + bflo(q.y) * wd.z +
               bfhi(q.y) * wd.w;
#pragma unroll
    for (int off = 1; off <= 32; off <<= 1) p0 += __shfl_xor(p0, off);
    if (lane == 0 && id0 >= 0) out[id0] = p0 + b;
  }
}

__global__ __launch_bounds__(256) void node_pred_kernel(
    const unsigned short* __restrict__ h2b, const float* __restrict__ Wn,
    const float* __restrict__ bn, float* __restrict__ out) {
  int n = blockIdx.x * 4 + (threadIdx.x >> 6);
  if (n >= NN) return;
  int lane = threadIdx.x & 63;
  uint2 q = ((const uint2*)(h2b + (size_t)n * HC))[lane];
  float4 wn = *(const float4*)(Wn + lane * 4);
  float p = bflo(q.x) * wn.x + bfhi(q.x) * wn.y + bflo(q.y) * wn.z +
            bfhi(q.y) * wn.w;
#pragma unroll
  for (int off = 1; off <= 32; off <<= 1) p += __shfl_xor(p, off);
  if (lane == 0) out[n] = p;
}

extern "C" void kernel_launch(void* const* d_in, const int* in_sizes, int n_in,
                              void* d_out, int out_size, void* d_ws, size_t ws_size,
                              hipStream_t stream) {
  const float* x  = (const float*)d_in[0];
  const int* ei   = (const int*)d_in[1];
  const float* W1 = (const float*)d_in[3];
  const float* as1 = (const float*)d_in[4];
  const float* ad1 = (const float*)d_in[5];
  const float* b1 = (const float*)d_in[6];
  const float* W2 = (const float*)d_in[7];
  const float* as2 = (const float*)d_in[8];
  const float* ad2 = (const float*)d_in[9];
  const float* b2 = (const float*)d_in[10];
  const float* We = (const float*)d_in[11];
  const float* be = (const float*)d_in[12];
  const float* Wn = (const float*)d_in[13];
  const float* bn = (const float*)d_in[14];
  float* out = (float*)d_out;

  char* wsp = (char*)d_ws;
  auto alloc = [&](size_t bytes) {
    char* p = wsp;
    wsp += (bytes + 255) & ~(size_t)255;
    return p;
  };
  float* bufA = (float*)alloc((size_t)NN * HC * 4);                  // gemm out fp32 (both layers)
  unsigned short* hbA = (unsigned short*)alloc((size_t)NN * HC * 2); // gemm out bf16 (both layers)
  unsigned short* h1h = (unsigned short*)alloc((size_t)NN * HC * 2); // agg1 out hi  (xh aliases front)
  unsigned short* h1l = (unsigned short*)alloc((size_t)NN * HC * 2); // agg1 out lo  (xl aliases front)
  unsigned short* hbB = (unsigned short*)alloc((size_t)NN * HC * 2); // agg2 out bf16
  float* a_s = (float*)alloc((size_t)NN * 8 * 4);
  float* a_d = (float*)alloc((size_t)NN * 8 * 4);
  int* rowptr = (int*)alloc((size_t)(NN + 1) * 4);
  int* colv = (int*)alloc((size_t)(NE + NN) * 4);
  int* eidv = (int*)alloc((size_t)(NE + NN) * 4);
  int* counts = (int*)alloc((size_t)NN * 4);   // also reused for W1t after CSR build
  int* tmp = (int*)alloc((size_t)NN * 4);      // also reused for W2t after CSR build
  int* scanbuf = (int*)alloc((size_t)NN * 4);  // also reused for W2t after CSR build
  int* bsum = (int*)alloc(256 * 4);
  int* boff = (int*)alloc(256 * 4);

  // aliases (lifetimes disjoint):
  unsigned short* xh = h1h;  // x hi/lo dead before agg1 writes h1h/h1l
  unsigned short* xl = h1l;
  // W transposed hi/lo overlay the dead CSR scratch (counts/tmp/scanbuf = 600 KB >= 393 KB)
  unsigned short* W1th = (unsigned short*)counts;                 // 64 KB
  unsigned short* W1tl = (unsigned short*)counts + FIN * HC;      // 64 KB
  unsigned short* W2th = (unsigned short*)tmp;                    // 128 KB
  unsigned short* W2tl = (unsigned short*)scanbuf;                // 128 KB

  const int NB = (NN + 255) / 256;

  // CSR build (uses counts/tmp/scanbuf BEFORE the W overlays are written)
  init_counts<<<NB, 256, 0, stream>>>(counts, tmp);
  hist_kernel<<<(NE + 255) / 256, 256, 0, stream>>>(ei, counts);
  scan1<<<NB, 256, 0, stream>>>(counts, scanbuf, bsum);
  scan2<<<1, 256, 0, stream>>>(bsum, boff, NB);
  scan3<<<NB, 256, 0, stream>>>(scanbuf, boff, rowptr);
  scatter_kernel<<<(NE + NN + 255) / 256, 256, 0, stream>>>(ei, rowptr, tmp, colv, eidv);

  // conversions (after CSR build so the scratch overlay is safe)
  convert_x<<<(NN * FIN / 4 + 255) / 256, 256, 0, stream>>>(x, xh, xl, NN * FIN / 4);
  convert_w<<<(FIN * HC + 255) / 256, 256, 0, stream>>>(W1, W1th, W1tl, FIN);
  convert_w<<<(HC * HC + 255) / 256, 256, 0, stream>>>(W2, W2th, W2tl, HC);

  dim3 ggrid((NN + 127) / 128, 2);  // 391 x 2

  // layer 1
  gemm_mfma<<<ggrid, 256, 0, stream>>>(xh, xl, W1th, W1tl, bufA, hbA, NN, FIN);
  coef_kernel<<<NN / 4, 256, 0, stream>>>(bufA, as1, ad1, a_s, a_d);
  agg_kernel<<<NN / 4, 256, 0, stream>>>(hbA, a_s, a_d, rowptr, colv, b1,
                                         (float*)nullptr, (unsigned short*)nullptr,
                                         h1h, h1l);

  // layer 2
  gemm_mfma<<<ggrid, 256, 0, stream>>>(h1h, h1l, W2th, W2tl, bufA, hbA, NN, HC);
  coef_kernel<<<NN / 4, 256, 0, stream>>>(bufA, as2, ad2, a_s, a_d);
  agg_kernel<<<NN / 4, 256, 0, stream>>>(hbA, a_s, a_d, rowptr, colv, b2,
                                         (float*)nullptr, hbB,
                                         (unsigned short*)nullptr, (unsigned short*)nullptr);

  // predictions
  edge_pred_kernel<<<NN / 4, 256, 0, stream>>>(hbB, rowptr, colv, eidv, We, be, out);
  node_pred_kernel<<<NN / 4, 256, 0, stream>>>(hbB, Wn, bn, out + NE);
}